// Round 11
// baseline (5012.248 us; speedup 1.0000x reference)
//
#include <hip/hip_runtime.h>
#include <hip/hip_bf16.h>

typedef unsigned short u16;
typedef unsigned int u32;
typedef unsigned long long u64;

#define HD 512
#define BATCH 128
#define TENC 512
#define WPAD 520   // LDS row stride in bf16 elems (even -> u32-aligned rows)

typedef float f32x4 __attribute__((ext_vector_type(4)));
typedef short s16x8 __attribute__((ext_vector_type(8)));

__device__ __forceinline__ u16 f2b(float f) {
    u32 u = __float_as_uint(f);
    u32 r = (u + 0x7FFFu + ((u >> 16) & 1u)) >> 16;   // RNE
    return (u16)r;
}
__device__ __forceinline__ float b2f(u16 h) {
    return __uint_as_float(((u32)h) << 16);
}
__device__ __forceinline__ float sigm(float z) { return 1.0f / (1.0f + __expf(-z)); }
__device__ __forceinline__ float tanh_f(float z) { return 1.0f - 2.0f / (__expf(2.0f * z) + 1.0f); }

// ---------------------------------------------------------------------------
// init: seed tagged h-buffer. Layout: hb64[(g*2+parity)*4096 + b*256 + jp]
//   word = (bf16 h[2jp] | bf16 h[2jp+1]<<16) | ((u64)tag << 32)
// parity0 holds h_0 with tag 0; parity1 zeroed (tag 0, never matches t>=1).
// Also build rnn_Whh transposed bf16 [k][j] for coalesced decoder reads.
// ---------------------------------------------------------------------------
__global__ void init_misc(const float* __restrict__ h0, const float* __restrict__ rWhh,
                          u64* __restrict__ hb64, u16* __restrict__ rT) {
    int idx = blockIdx.x * 256 + threadIdx.x;      // 512 blocks x 256 = 131072
    if (idx < 65536) {                              // 8 g x 2 parity x 4096 words
        int g   = idx >> 13;
        int r   = idx & 8191;
        int p   = r >> 12;
        int ofs = r & 4095;
        int b   = ofs >> 8, jp = ofs & 255;
        u64 v = 0ull;                               // tag 0
        if (p == 0) {
            const float* hrow = h0 + (size_t)(g * 16 + b) * HD + jp * 2;
            u32 lo = (u32)f2b(hrow[0]) | ((u32)f2b(hrow[1]) << 16);
            v = (u64)lo;                            // tag 0 for h_0
        }
        hb64[(size_t)(g * 2 + p) * 4096 + b * 256 + jp] = v;
    }
    for (int i = idx; i < 262144; i += 131072) {    // rT[k*512+j] = rWhh[j][k]
        int k = i >> 9, j = i & 511;
        rT[i] = f2b(rWhh[j * 512 + k]);
    }
}

// ---------------------------------------------------------------------------
// Encoder LSTM: 8 batch-groups x 16 wgs -- EXACT round-6 proven kernel.
// Cross-wg h handoff via SELF-VALIDATING tagged 64-bit words: {bf16 pair,
// step tag} in one atomic dwordx2 agent-scope store. Readers poll the data
// words until tag==t. Parity-2 buffering.
// ---------------------------------------------------------------------------
__global__ __launch_bounds__(512, 2) void enc_lstm(
    const float* __restrict__ xseq, const float* __restrict__ c0,
    const float* __restrict__ Wih, const float* __restrict__ Whh,
    const float* __restrict__ bih, const float* __restrict__ bhh,
    u16* __restrict__ enc, u64* __restrict__ hb64) {

    __shared__ u16 hlds[16 * WPAD];     // 16640 B: staged h tile [16b][512k] bf16
    __shared__ float exg[16 * 132];     // 8448 B: gate pre-activations [b][128 rows]
    __shared__ float bias_l[128];
    __shared__ float wih_l[128];

    const int tid = threadIdx.x;
    const int g = blockIdx.x & 7;       // batch group
    const int sl = blockIdx.x >> 3;     // hidden slot 0..15

    if (tid < 128) {
        int n = (tid >> 5) * 512 + sl * 32 + (tid & 31);
        bias_l[tid] = bih[n] + bhh[n];
        wih_l[tid] = Wih[n];
    }

    const int bT = tid >> 5, jl = tid & 31;               // cell-update mapping
    float c = c0[(g * 16 + bT) * HD + sl * 32 + jl];      // persistent cell state

    const int lane = tid & 63, wv = tid >> 6;
    const int q = lane >> 4, cl = lane & 15;
    const int R = (wv >> 1) * 32 + (wv & 1) * 16;         // wave's 16 gate-rows

    // hoist this lane's 16 B-fragments of Whh into registers (64 VGPRs)
    s16x8 bw[16];
    {
        int r = R + cl;
        int grow = (r >> 5) * 512 + sl * 32 + (r & 31);
        const float* wrow = Whh + (size_t)grow * 512;
        #pragma unroll
        for (int ks = 0; ks < 16; ++ks) {
            s16x8 v;
            #pragma unroll
            for (int j = 0; j < 8; ++j)
                v[j] = (short)f2b(wrow[ks * 32 + q * 8 + j]);
            bw[ks] = v;
        }
    }

    u32* hlds32 = (u32*)hlds;
    __syncthreads();

    const int jgl = sl * 32 + jl;
    u64* dpl0 = hb64 + (size_t)(g * 2) * 4096 + bT * 256 + (jgl >> 1);
    u64* dpl1 = dpl0 + 4096;

    for (int t = 0; t < TENC; ++t) {
        // ---- stage h_t: poll tagged words of buf[t&1] until tag==t
        const u64* src = hb64 + (size_t)(g * 2 + (t & 1)) * 4096;
        const u32 want = (u32)t;
        u64 vv[8];
        #pragma unroll
        for (int i = 0; i < 8; ++i)
            vv[i] = __hip_atomic_load(src + tid + i * 512, __ATOMIC_RELAXED,
                                      __HIP_MEMORY_SCOPE_AGENT);
        float xv = xseq[t * BATCH + g * 16 + bT];   // prefetched; used post-MFMA
        for (;;) {
            bool ok = true;
            #pragma unroll
            for (int i = 0; i < 8; ++i) {
                if ((u32)(vv[i] >> 32) != want) {
                    ok = false;
                    vv[i] = __hip_atomic_load(src + tid + i * 512, __ATOMIC_RELAXED,
                                              __HIP_MEMORY_SCOPE_AGENT);
                }
            }
            if (ok) break;
        }
        #pragma unroll
        for (int i = 0; i < 8; ++i) {
            int idx = tid + i * 512;
            hlds32[(idx >> 8) * 260 + (idx & 255)] = (u32)vv[i];
        }
        __syncthreads();                            // S1: hlds ready

        // dual accumulators: halve the dependent MFMA chain
        f32x4 acc0 = {0.f, 0.f, 0.f, 0.f}, acc1 = {0.f, 0.f, 0.f, 0.f};
        #pragma unroll
        for (int ks = 0; ks < 16; ks += 2) {
            s16x8 av0 = *(const s16x8*)&hlds[cl * WPAD + ks * 32 + q * 8];
            s16x8 av1 = *(const s16x8*)&hlds[cl * WPAD + (ks + 1) * 32 + q * 8];
            acc0 = __builtin_amdgcn_mfma_f32_16x16x32_bf16(av0, bw[ks], acc0, 0, 0, 0);
            acc1 = __builtin_amdgcn_mfma_f32_16x16x32_bf16(av1, bw[ks + 1], acc1, 0, 0, 0);
        }
        f32x4 acc = acc0 + acc1;
        #pragma unroll
        for (int r4 = 0; r4 < 4; ++r4)
            exg[(q * 4 + r4) * 132 + R + cl] = acc[r4];   // D: row m=q*4+r4, col n=cl
        __syncthreads();                            // S2: exg ready + hlds reads done

        // LSTM cell for (bT, jl)
        const float* exb = &exg[bT * 132];
        float gi = exb[jl]      + xv * wih_l[jl]      + bias_l[jl];
        float gf = exb[32 + jl] + xv * wih_l[32 + jl] + bias_l[32 + jl];
        float gg = exb[64 + jl] + xv * wih_l[64 + jl] + bias_l[64 + jl];
        float go = exb[96 + jl] + xv * wih_l[96 + jl] + bias_l[96 + jl];
        c = sigm(gf) * c + sigm(gi) * tanh_f(gg);
        float hv = sigm(go) * tanh_f(c);
        u16 h16 = f2b(hv);

        // tagged h_{t+1} store: pair + tag in ONE atomic 8B store (critical path)
        u32 me = (u32)h16;
        u32 up = (u32)__shfl_down((int)me, 1, 64);
        if ((jl & 1) == 0) {
            u64 word = (u64)(me | (up << 16)) | ((u64)(u32)(t + 1) << 32);
            __hip_atomic_store(((t + 1) & 1) ? dpl1 : dpl0, word,
                               __ATOMIC_RELAXED, __HIP_MEMORY_SCOPE_AGENT);
        }
        // enc write AFTER the handoff store: off the critical path
        enc[((size_t)t * BATCH + g * 16 + bT) * HD + jgl] = h16;
    }
}

// ---------------------------------------------------------------------------
// Fused decoder: one wg per batch row, 32 steps. p2: 2-buffer A/B rename
// pipeline (issue 0,1 before p1) with DOUBLE-UNPACK procit -- e[8] is
// transient per row (liveness 8 floats, not 64): unpack once for the dot,
// butterflies batched, unpack again from the still-live uint4s for the acc
// update. Live set ~110 VGPR: NO SPILL (round-10 spilled 94MB to scratch).
// ---------------------------------------------------------------------------
__global__ __launch_bounds__(512, 1) void dec_all(
    const float* __restrict__ xlast, const u16* __restrict__ enc,
    const u16* __restrict__ rT, const float* __restrict__ rWih,
    const float* __restrict__ rbih, const float* __restrict__ rbhh,
    const float* __restrict__ linW, const float* __restrict__ linb,
    float* __restrict__ dout) {

    __shared__ float hp[512];          // h entering the step
    __shared__ float ctxl[8 * 512];    // p1 partials, then p2 ctx partials
    __shared__ float red[512];         // hn broadcast, then reduce slots
    __shared__ float mw[8], lw[8];
    __shared__ float xsh;

    const int tid = threadIdx.x;
    const int b = blockIdx.x;
    const int wv = tid >> 6, lane = tid & 63;

    hp[tid] = b2f(enc[(size_t)511 * BATCH * HD + b * HD + tid]);  // h_enc
    float x = xlast[b];
    const float bia = rbih[tid] + rbhh[tid];
    const float wih = rWih[tid];
    const float lwt = linW[tid];
    const float lb = linb[0];
    const uint4* rT4 = (const uint4*)rT;                 // [512 k][64 chunks]
    const u16* ebase = enc + (size_t)b * HD + lane * 8;  // t-stride = 65536 elems
    __syncthreads();

    for (int s = 0; s < 32; ++s) {
        float m = -1e30f, l = 0.f;
        float acc[8] = {0, 0, 0, 0, 0, 0, 0, 0};
        float h8[8];
        uint4 bA[8], bB[8];

        auto issue = [&](uint4* bf, int it) {
            #pragma unroll
            for (int i = 0; i < 8; ++i)
                bf[i] = *(const uint4*)(ebase +
                          (size_t)(it * 64 + i * 8 + wv) * 65536);
        };
        auto procit = [&](const uint4* bf) {
            float sp[8];
            #pragma unroll
            for (int i = 0; i < 8; ++i) {            // pass 1: transient unpack
                uint4 ev = bf[i];
                float sd = 0.f;
                sd = fmaf(b2f((u16)(ev.x & 0xFFFF)), h8[0], sd);
                sd = fmaf(b2f((u16)(ev.x >> 16)),    h8[1], sd);
                sd = fmaf(b2f((u16)(ev.y & 0xFFFF)), h8[2], sd);
                sd = fmaf(b2f((u16)(ev.y >> 16)),    h8[3], sd);
                sd = fmaf(b2f((u16)(ev.z & 0xFFFF)), h8[4], sd);
                sd = fmaf(b2f((u16)(ev.z >> 16)),    h8[5], sd);
                sd = fmaf(b2f((u16)(ev.w & 0xFFFF)), h8[6], sd);
                sd = fmaf(b2f((u16)(ev.w >> 16)),    h8[7], sd);
                sp[i] = sd;
            }
            // batched butterfly: 6 dependent stages, 8-way ILP
            #pragma unroll
            for (int mk = 1; mk < 64; mk <<= 1) {
                #pragma unroll
                for (int i = 0; i < 8; ++i) sp[i] += __shfl_xor(sp[i], mk, 64);
            }
            float pm = sp[0];
            #pragma unroll
            for (int i = 1; i < 8; ++i) pm = fmaxf(pm, sp[i]);
            if (pm > m) {                           // one rescale per 8-t block
                float sc = __expf(m - pm);
                l *= sc;
                #pragma unroll
                for (int j = 0; j < 8; ++j) acc[j] *= sc;
                m = pm;
            }
            #pragma unroll
            for (int i = 0; i < 8; ++i) {            // pass 2: re-unpack for acc
                float p = __expf(sp[i] - m);
                l += p;
                uint4 ev = bf[i];
                acc[0] = fmaf(p, b2f((u16)(ev.x & 0xFFFF)), acc[0]);
                acc[1] = fmaf(p, b2f((u16)(ev.x >> 16)),    acc[1]);
                acc[2] = fmaf(p, b2f((u16)(ev.y & 0xFFFF)), acc[2]);
                acc[3] = fmaf(p, b2f((u16)(ev.y >> 16)),    acc[3]);
                acc[4] = fmaf(p, b2f((u16)(ev.z & 0xFFFF)), acc[4]);
                acc[5] = fmaf(p, b2f((u16)(ev.z >> 16)),    acc[5]);
                acc[6] = fmaf(p, b2f((u16)(ev.w & 0xFFFF)), acc[6]);
                acc[7] = fmaf(p, b2f((u16)(ev.w >> 16)),    acc[7]);
            }
        };

        // prologue prefetch: its 0,1 in flight across all of p1
        issue(bA, 0);
        issue(bB, 1);

        // ---- phase 1: wave wv covers k in [wv*64, wv*64+64)
        float pa[8] = {0, 0, 0, 0, 0, 0, 0, 0};
        const uint4* base = rT4 + (size_t)(wv * 64) * 64 + lane;
        #pragma unroll 4
        for (int kk = 0; kk < 64; ++kk) {
            float hk = hp[wv * 64 + kk];
            uint4 w = base[kk * 64];
            pa[0] = fmaf(hk, b2f((u16)(w.x & 0xFFFF)), pa[0]);
            pa[1] = fmaf(hk, b2f((u16)(w.x >> 16)),    pa[1]);
            pa[2] = fmaf(hk, b2f((u16)(w.y & 0xFFFF)), pa[2]);
            pa[3] = fmaf(hk, b2f((u16)(w.y >> 16)),    pa[3]);
            pa[4] = fmaf(hk, b2f((u16)(w.z & 0xFFFF)), pa[4]);
            pa[5] = fmaf(hk, b2f((u16)(w.z >> 16)),    pa[5]);
            pa[6] = fmaf(hk, b2f((u16)(w.w & 0xFFFF)), pa[6]);
            pa[7] = fmaf(hk, b2f((u16)(w.w >> 16)),    pa[7]);
        }
        #pragma unroll
        for (int i = 0; i < 8; ++i) ctxl[wv * 512 + lane * 8 + i] = pa[i];
        __syncthreads();

        float a = bia + x * wih;
        #pragma unroll
        for (int i = 0; i < 8; ++i) a += ctxl[i * 512 + tid];
        float hv = tanh_f(a);
        red[tid] = hv;                  // hn broadcast
        __syncthreads();

        // ---- phase 2: wave wv handles t = it*64 + i*8 + wv, A/B rename
        #pragma unroll
        for (int i = 0; i < 8; ++i) h8[i] = red[lane * 8 + i];

        procit(bA); issue(bA, 2);
        procit(bB); issue(bB, 3);
        procit(bA); issue(bA, 4);
        procit(bB); issue(bB, 5);
        procit(bA); issue(bA, 6);
        procit(bB); issue(bB, 7);
        procit(bA);
        procit(bB);

        if (lane == 0) { mw[wv] = m; lw[wv] = l; }
        #pragma unroll
        for (int i = 0; i < 8; ++i) ctxl[wv * HD + lane * 8 + i] = acc[i];
        __syncthreads();

        // ---- phase 3: merge online-softmax states, project, relu
        float M = mw[0];
        #pragma unroll
        for (int i = 1; i < 8; ++i) M = fmaxf(M, mw[i]);
        float L = 0.f, aw[8];
        #pragma unroll
        for (int i = 0; i < 8; ++i) { aw[i] = __expf(mw[i] - M); L += aw[i] * lw[i]; }
        float cj = 0.f;
        #pragma unroll
        for (int i = 0; i < 8; ++i) cj = fmaf(aw[i], ctxl[i * HD + tid], cj);
        float r = cj * lwt;
        #pragma unroll
        for (int mk = 1; mk < 64; mk <<= 1) r += __shfl_xor(r, mk, 64);
        if (lane == 0) red[wv] = r;
        __syncthreads();
        if (tid == 0) {
            float o = (red[0] + red[1] + red[2] + red[3] +
                       red[4] + red[5] + red[6] + red[7]) / L + lb;
            o = fmaxf(o, 0.f);
            dout[s * BATCH + b] = o;
            xsh = o;
        }
        __syncthreads();
        x = xsh;
        hp[tid] = hv;                   // h for next step
        __syncthreads();
    }
}

// ---------------------------------------------------------------------------
extern "C" void kernel_launch(void* const* d_in, const int* in_sizes, int n_in,
                              void* d_out, int out_size, void* d_ws, size_t ws_size,
                              hipStream_t stream) {
    const float* xseq = (const float*)d_in[0];   // [513,128,1]
    const float* h0   = (const float*)d_in[1];
    const float* c0   = (const float*)d_in[2];
    const float* Wih  = (const float*)d_in[3];   // [2048,1]
    const float* Whh  = (const float*)d_in[4];   // [2048,512]
    const float* bih  = (const float*)d_in[5];
    const float* bhh  = (const float*)d_in[6];
    const float* rWih = (const float*)d_in[7];   // [512,1]
    const float* rWhh = (const float*)d_in[8];   // [512,512]
    const float* rbih = (const float*)d_in[9];
    const float* rbhh = (const float*)d_in[10];
    const float* linW = (const float*)d_in[11];  // [1,512]
    const float* linb = (const float*)d_in[12];
    float* dout = (float*)d_out;                 // [32,128,1]

    // workspace layout
    char* ws = (char*)d_ws;
    u16* enc  = (u16*)ws;                                  // 64 MB
    u16* rT   = (u16*)(ws + 67108864);                     // 512 KB
    u64* hb64 = (u64*)(ws + 67108864 + 524288);            // 512 KB tagged h

    init_misc<<<512, 256, 0, stream>>>(h0, rWhh, hb64, rT);
    enc_lstm<<<128, 512, 0, stream>>>(xseq, c0, Wih, Whh, bih, bhh, enc, hb64);
    dec_all<<<128, 512, 0, stream>>>(xseq + 512 * BATCH, enc, rT, rWih,
                                     rbih, rbhh, linW, linb, dout);
}

// Round 12
// 5011.800 us; speedup vs baseline: 1.0001x; 1.0001x over previous
//
#include <hip/hip_runtime.h>
#include <hip/hip_bf16.h>

typedef unsigned short u16;
typedef unsigned int u32;
typedef unsigned long long u64;

#define HD 512
#define BATCH 128
#define TENC 512
#define WPAD 520   // LDS row stride in bf16 elems (even -> u32-aligned rows)

typedef float f32x4 __attribute__((ext_vector_type(4)));
typedef short s16x8 __attribute__((ext_vector_type(8)));

__device__ __forceinline__ u16 f2b(float f) {
    u32 u = __float_as_uint(f);
    u32 r = (u + 0x7FFFu + ((u >> 16) & 1u)) >> 16;   // RNE
    return (u16)r;
}
__device__ __forceinline__ float b2f(u16 h) {
    return __uint_as_float(((u32)h) << 16);
}
__device__ __forceinline__ float sigm(float z) { return 1.0f / (1.0f + __expf(-z)); }
__device__ __forceinline__ float tanh_f(float z) { return 1.0f - 2.0f / (__expf(2.0f * z) + 1.0f); }

// ---------------------------------------------------------------------------
// init: seed tagged h-buffer. Layout: hb64[(g*2+parity)*4096 + b*256 + jp]
//   word = (bf16 h[2jp] | bf16 h[2jp+1]<<16) | ((u64)tag << 32)
// parity0 holds h_0 with tag 0; parity1 zeroed (tag 0, never matches t>=1).
// Also build rnn_Whh transposed bf16 [k][j] for coalesced decoder reads.
// ---------------------------------------------------------------------------
__global__ void init_misc(const float* __restrict__ h0, const float* __restrict__ rWhh,
                          u64* __restrict__ hb64, u16* __restrict__ rT) {
    int idx = blockIdx.x * 256 + threadIdx.x;      // 512 blocks x 256 = 131072
    if (idx < 65536) {                              // 8 g x 2 parity x 4096 words
        int g   = idx >> 13;
        int r   = idx & 8191;
        int p   = r >> 12;
        int ofs = r & 4095;
        int b   = ofs >> 8, jp = ofs & 255;
        u64 v = 0ull;                               // tag 0
        if (p == 0) {
            const float* hrow = h0 + (size_t)(g * 16 + b) * HD + jp * 2;
            u32 lo = (u32)f2b(hrow[0]) | ((u32)f2b(hrow[1]) << 16);
            v = (u64)lo;                            // tag 0 for h_0
        }
        hb64[(size_t)(g * 2 + p) * 4096 + b * 256 + jp] = v;
    }
    for (int i = idx; i < 262144; i += 131072) {    // rT[k*512+j] = rWhh[j][k]
        int k = i >> 9, j = i & 511;
        rT[i] = f2b(rWhh[j * 512 + k]);
    }
}

// ---------------------------------------------------------------------------
// Encoder LSTM: 8 batch-groups x 16 wgs -- EXACT round-6 proven kernel.
// Cross-wg h handoff via SELF-VALIDATING tagged 64-bit words: {bf16 pair,
// step tag} in one atomic dwordx2 agent-scope store. Readers poll the data
// words until tag==t. Parity-2 buffering.
// ---------------------------------------------------------------------------
__global__ __launch_bounds__(512, 2) void enc_lstm(
    const float* __restrict__ xseq, const float* __restrict__ c0,
    const float* __restrict__ Wih, const float* __restrict__ Whh,
    const float* __restrict__ bih, const float* __restrict__ bhh,
    u16* __restrict__ enc, u64* __restrict__ hb64) {

    __shared__ u16 hlds[16 * WPAD];     // 16640 B: staged h tile [16b][512k] bf16
    __shared__ float exg[16 * 132];     // 8448 B: gate pre-activations [b][128 rows]
    __shared__ float bias_l[128];
    __shared__ float wih_l[128];

    const int tid = threadIdx.x;
    const int g = blockIdx.x & 7;       // batch group
    const int sl = blockIdx.x >> 3;     // hidden slot 0..15

    if (tid < 128) {
        int n = (tid >> 5) * 512 + sl * 32 + (tid & 31);
        bias_l[tid] = bih[n] + bhh[n];
        wih_l[tid] = Wih[n];
    }

    const int bT = tid >> 5, jl = tid & 31;               // cell-update mapping
    float c = c0[(g * 16 + bT) * HD + sl * 32 + jl];      // persistent cell state

    const int lane = tid & 63, wv = tid >> 6;
    const int q = lane >> 4, cl = lane & 15;
    const int R = (wv >> 1) * 32 + (wv & 1) * 16;         // wave's 16 gate-rows

    // hoist this lane's 16 B-fragments of Whh into registers (64 VGPRs)
    s16x8 bw[16];
    {
        int r = R + cl;
        int grow = (r >> 5) * 512 + sl * 32 + (r & 31);
        const float* wrow = Whh + (size_t)grow * 512;
        #pragma unroll
        for (int ks = 0; ks < 16; ++ks) {
            s16x8 v;
            #pragma unroll
            for (int j = 0; j < 8; ++j)
                v[j] = (short)f2b(wrow[ks * 32 + q * 8 + j]);
            bw[ks] = v;
        }
    }

    u32* hlds32 = (u32*)hlds;
    __syncthreads();

    const int jgl = sl * 32 + jl;
    u64* dpl0 = hb64 + (size_t)(g * 2) * 4096 + bT * 256 + (jgl >> 1);
    u64* dpl1 = dpl0 + 4096;

    for (int t = 0; t < TENC; ++t) {
        // ---- stage h_t: poll tagged words of buf[t&1] until tag==t
        const u64* src = hb64 + (size_t)(g * 2 + (t & 1)) * 4096;
        const u32 want = (u32)t;
        u64 vv[8];
        #pragma unroll
        for (int i = 0; i < 8; ++i)
            vv[i] = __hip_atomic_load(src + tid + i * 512, __ATOMIC_RELAXED,
                                      __HIP_MEMORY_SCOPE_AGENT);
        float xv = xseq[t * BATCH + g * 16 + bT];   // prefetched; used post-MFMA
        for (;;) {
            bool ok = true;
            #pragma unroll
            for (int i = 0; i < 8; ++i) {
                if ((u32)(vv[i] >> 32) != want) {
                    ok = false;
                    vv[i] = __hip_atomic_load(src + tid + i * 512, __ATOMIC_RELAXED,
                                              __HIP_MEMORY_SCOPE_AGENT);
                }
            }
            if (ok) break;
        }
        #pragma unroll
        for (int i = 0; i < 8; ++i) {
            int idx = tid + i * 512;
            hlds32[(idx >> 8) * 260 + (idx & 255)] = (u32)vv[i];
        }
        __syncthreads();                            // S1: hlds ready

        // dual accumulators: halve the dependent MFMA chain
        f32x4 acc0 = {0.f, 0.f, 0.f, 0.f}, acc1 = {0.f, 0.f, 0.f, 0.f};
        #pragma unroll
        for (int ks = 0; ks < 16; ks += 2) {
            s16x8 av0 = *(const s16x8*)&hlds[cl * WPAD + ks * 32 + q * 8];
            s16x8 av1 = *(const s16x8*)&hlds[cl * WPAD + (ks + 1) * 32 + q * 8];
            acc0 = __builtin_amdgcn_mfma_f32_16x16x32_bf16(av0, bw[ks], acc0, 0, 0, 0);
            acc1 = __builtin_amdgcn_mfma_f32_16x16x32_bf16(av1, bw[ks + 1], acc1, 0, 0, 0);
        }
        f32x4 acc = acc0 + acc1;
        #pragma unroll
        for (int r4 = 0; r4 < 4; ++r4)
            exg[(q * 4 + r4) * 132 + R + cl] = acc[r4];   // D: row m=q*4+r4, col n=cl
        __syncthreads();                            // S2: exg ready + hlds reads done

        // LSTM cell for (bT, jl)
        const float* exb = &exg[bT * 132];
        float gi = exb[jl]      + xv * wih_l[jl]      + bias_l[jl];
        float gf = exb[32 + jl] + xv * wih_l[32 + jl] + bias_l[32 + jl];
        float gg = exb[64 + jl] + xv * wih_l[64 + jl] + bias_l[64 + jl];
        float go = exb[96 + jl] + xv * wih_l[96 + jl] + bias_l[96 + jl];
        c = sigm(gf) * c + sigm(gi) * tanh_f(gg);
        float hv = sigm(go) * tanh_f(c);
        u16 h16 = f2b(hv);

        // tagged h_{t+1} store: pair + tag in ONE atomic 8B store (critical path)
        u32 me = (u32)h16;
        u32 up = (u32)__shfl_down((int)me, 1, 64);
        if ((jl & 1) == 0) {
            u64 word = (u64)(me | (up << 16)) | ((u64)(u32)(t + 1) << 32);
            __hip_atomic_store(((t + 1) & 1) ? dpl1 : dpl0, word,
                               __ATOMIC_RELAXED, __HIP_MEMORY_SCOPE_AGENT);
        }
        // enc write AFTER the handoff store: off the critical path
        enc[((size_t)t * BATCH + g * 16 + bT) * HD + jgl] = h16;
    }
}

// ---------------------------------------------------------------------------
// Fused decoder: one wg per batch row, 32 steps.
// p2: A/B depth-2 pipeline CONFINED TO p2 (nothing held across p1 or any
// __syncthreads -- barriers drain vmcnt(0), and cross-p1 liveness caused the
// round-10/11 128-VGPR spill + 94MB scratch). Double-unpack PROC (transient
// e, liveness 8 floats). Macros, no lambdas. Peak liveness ~110 in p2,
// ~75 in p1: no spill.
// ---------------------------------------------------------------------------
#define DEC_ISSUE(BF, IT)                                                    \
    do {                                                                     \
        _Pragma("unroll")                                                    \
        for (int i_ = 0; i_ < 8; ++i_)                                       \
            BF[i_] = *(const uint4*)(ebase +                                 \
                       (size_t)((IT) * 64 + i_ * 8 + wv) * 65536);           \
    } while (0)

#define DEC_PROC(BF)                                                         \
    do {                                                                     \
        float sp_[8];                                                        \
        _Pragma("unroll")                                                    \
        for (int i_ = 0; i_ < 8; ++i_) {            /* pass 1: dot */        \
            uint4 ev = BF[i_];                                               \
            float sd = 0.f;                                                  \
            sd = fmaf(b2f((u16)(ev.x & 0xFFFF)), h8[0], sd);                 \
            sd = fmaf(b2f((u16)(ev.x >> 16)),    h8[1], sd);                 \
            sd = fmaf(b2f((u16)(ev.y & 0xFFFF)), h8[2], sd);                 \
            sd = fmaf(b2f((u16)(ev.y >> 16)),    h8[3], sd);                 \
            sd = fmaf(b2f((u16)(ev.z & 0xFFFF)), h8[4], sd);                 \
            sd = fmaf(b2f((u16)(ev.z >> 16)),    h8[5], sd);                 \
            sd = fmaf(b2f((u16)(ev.w & 0xFFFF)), h8[6], sd);                 \
            sd = fmaf(b2f((u16)(ev.w >> 16)),    h8[7], sd);                 \
            sp_[i_] = sd;                                                    \
        }                                                                    \
        _Pragma("unroll")                           /* batched butterfly */  \
        for (int mk = 1; mk < 64; mk <<= 1) {                                \
            _Pragma("unroll")                                                \
            for (int i_ = 0; i_ < 8; ++i_) sp_[i_] += __shfl_xor(sp_[i_], mk, 64); \
        }                                                                    \
        float pm = sp_[0];                                                   \
        _Pragma("unroll")                                                    \
        for (int i_ = 1; i_ < 8; ++i_) pm = fmaxf(pm, sp_[i_]);              \
        if (pm > m) {                               /* one rescale / 8t */   \
            float sc = __expf(m - pm);                                       \
            l *= sc;                                                         \
            _Pragma("unroll")                                                \
            for (int j_ = 0; j_ < 8; ++j_) acc[j_] *= sc;                    \
            m = pm;                                                          \
        }                                                                    \
        _Pragma("unroll")                                                    \
        for (int i_ = 0; i_ < 8; ++i_) {            /* pass 2: re-unpack */  \
            float p = __expf(sp_[i_] - m);                                   \
            l += p;                                                          \
            uint4 ev = BF[i_];                                               \
            acc[0] = fmaf(p, b2f((u16)(ev.x & 0xFFFF)), acc[0]);             \
            acc[1] = fmaf(p, b2f((u16)(ev.x >> 16)),    acc[1]);             \
            acc[2] = fmaf(p, b2f((u16)(ev.y & 0xFFFF)), acc[2]);             \
            acc[3] = fmaf(p, b2f((u16)(ev.y >> 16)),    acc[3]);             \
            acc[4] = fmaf(p, b2f((u16)(ev.z & 0xFFFF)), acc[4]);             \
            acc[5] = fmaf(p, b2f((u16)(ev.z >> 16)),    acc[5]);             \
            acc[6] = fmaf(p, b2f((u16)(ev.w & 0xFFFF)), acc[6]);             \
            acc[7] = fmaf(p, b2f((u16)(ev.w >> 16)),    acc[7]);             \
        }                                                                    \
    } while (0)

__global__ __launch_bounds__(512, 1) void dec_all(
    const float* __restrict__ xlast, const u16* __restrict__ enc,
    const u16* __restrict__ rT, const float* __restrict__ rWih,
    const float* __restrict__ rbih, const float* __restrict__ rbhh,
    const float* __restrict__ linW, const float* __restrict__ linb,
    float* __restrict__ dout) {

    __shared__ float hp[512];          // h entering the step
    __shared__ float ctxl[8 * 512];    // p1 partials, then p2 ctx partials
    __shared__ float red[512];         // hn broadcast, then reduce slots
    __shared__ float mw[8], lw[8];
    __shared__ float xsh;

    const int tid = threadIdx.x;
    const int b = blockIdx.x;
    const int wv = tid >> 6, lane = tid & 63;

    hp[tid] = b2f(enc[(size_t)511 * BATCH * HD + b * HD + tid]);  // h_enc
    float x = xlast[b];
    const float bia = rbih[tid] + rbhh[tid];
    const float wih = rWih[tid];
    const float lwt = linW[tid];
    const float lb = linb[0];
    const uint4* rT4 = (const uint4*)rT;                 // [512 k][64 chunks]
    const u16* ebase = enc + (size_t)b * HD + lane * 8;  // t-stride = 65536 elems
    __syncthreads();

    for (int s = 0; s < 32; ++s) {
        // ---- phase 1: wave wv covers k in [wv*64, wv*64+64)
        float pa[8] = {0, 0, 0, 0, 0, 0, 0, 0};
        const uint4* base = rT4 + (size_t)(wv * 64) * 64 + lane;
        #pragma unroll 4
        for (int kk = 0; kk < 64; ++kk) {
            float hk = hp[wv * 64 + kk];
            uint4 w = base[kk * 64];
            pa[0] = fmaf(hk, b2f((u16)(w.x & 0xFFFF)), pa[0]);
            pa[1] = fmaf(hk, b2f((u16)(w.x >> 16)),    pa[1]);
            pa[2] = fmaf(hk, b2f((u16)(w.y & 0xFFFF)), pa[2]);
            pa[3] = fmaf(hk, b2f((u16)(w.y >> 16)),    pa[3]);
            pa[4] = fmaf(hk, b2f((u16)(w.z & 0xFFFF)), pa[4]);
            pa[5] = fmaf(hk, b2f((u16)(w.z >> 16)),    pa[5]);
            pa[6] = fmaf(hk, b2f((u16)(w.w & 0xFFFF)), pa[6]);
            pa[7] = fmaf(hk, b2f((u16)(w.w >> 16)),    pa[7]);
        }
        #pragma unroll
        for (int i = 0; i < 8; ++i) ctxl[wv * 512 + lane * 8 + i] = pa[i];
        __syncthreads();

        float a = bia + x * wih;
        #pragma unroll
        for (int i = 0; i < 8; ++i) a += ctxl[i * 512 + tid];
        float hv = tanh_f(a);
        red[tid] = hv;                  // hn broadcast
        __syncthreads();

        // ---- phase 2: wave wv handles t = it*64 + i*8 + wv; A/B depth-2,
        // all state p2-local (nothing live across the barriers above)
        float h8[8];
        #pragma unroll
        for (int i = 0; i < 8; ++i) h8[i] = red[lane * 8 + i];
        float m = -1e30f, l = 0.f;
        float acc[8] = {0, 0, 0, 0, 0, 0, 0, 0};
        uint4 bA[8], bB[8];

        DEC_ISSUE(bA, 0);
        DEC_ISSUE(bB, 1);
        DEC_PROC(bA); DEC_ISSUE(bA, 2);
        DEC_PROC(bB); DEC_ISSUE(bB, 3);
        DEC_PROC(bA); DEC_ISSUE(bA, 4);
        DEC_PROC(bB); DEC_ISSUE(bB, 5);
        DEC_PROC(bA); DEC_ISSUE(bA, 6);
        DEC_PROC(bB); DEC_ISSUE(bB, 7);
        DEC_PROC(bA);
        DEC_PROC(bB);

        if (lane == 0) { mw[wv] = m; lw[wv] = l; }
        #pragma unroll
        for (int i = 0; i < 8; ++i) ctxl[wv * HD + lane * 8 + i] = acc[i];
        __syncthreads();

        // ---- phase 3: merge online-softmax states, project, relu
        float M = mw[0];
        #pragma unroll
        for (int i = 1; i < 8; ++i) M = fmaxf(M, mw[i]);
        float L = 0.f, aw[8];
        #pragma unroll
        for (int i = 0; i < 8; ++i) { aw[i] = __expf(mw[i] - M); L += aw[i] * lw[i]; }
        float cj = 0.f;
        #pragma unroll
        for (int i = 0; i < 8; ++i) cj = fmaf(aw[i], ctxl[i * HD + tid], cj);
        float r = cj * lwt;
        #pragma unroll
        for (int mk = 1; mk < 64; mk <<= 1) r += __shfl_xor(r, mk, 64);
        if (lane == 0) red[wv] = r;
        __syncthreads();
        if (tid == 0) {
            float o = (red[0] + red[1] + red[2] + red[3] +
                       red[4] + red[5] + red[6] + red[7]) / L + lb;
            o = fmaxf(o, 0.f);
            dout[s * BATCH + b] = o;
            xsh = o;
        }
        __syncthreads();
        x = xsh;
        hp[tid] = hv;                   // h for next step
        __syncthreads();
    }
}

// ---------------------------------------------------------------------------
extern "C" void kernel_launch(void* const* d_in, const int* in_sizes, int n_in,
                              void* d_out, int out_size, void* d_ws, size_t ws_size,
                              hipStream_t stream) {
    const float* xseq = (const float*)d_in[0];   // [513,128,1]
    const float* h0   = (const float*)d_in[1];
    const float* c0   = (const float*)d_in[2];
    const float* Wih  = (const float*)d_in[3];   // [2048,1]
    const float* Whh  = (const float*)d_in[4];   // [2048,512]
    const float* bih  = (const float*)d_in[5];
    const float* bhh  = (const float*)d_in[6];
    const float* rWih = (const float*)d_in[7];   // [512,1]
    const float* rWhh = (const float*)d_in[8];   // [512,512]
    const float* rbih = (const float*)d_in[9];
    const float* rbhh = (const float*)d_in[10];
    const float* linW = (const float*)d_in[11];  // [1,512]
    const float* linb = (const float*)d_in[12];
    float* dout = (float*)d_out;                 // [32,128,1]

    // workspace layout
    char* ws = (char*)d_ws;
    u16* enc  = (u16*)ws;                                  // 64 MB
    u16* rT   = (u16*)(ws + 67108864);                     // 512 KB
    u64* hb64 = (u64*)(ws + 67108864 + 524288);            // 512 KB tagged h

    init_misc<<<512, 256, 0, stream>>>(h0, rWhh, hb64, rT);
    enc_lstm<<<128, 512, 0, stream>>>(xseq, c0, Wih, Whh, bih, bhh, enc, hb64);
    dec_all<<<128, 512, 0, stream>>>(xseq + 512 * BATCH, enc, rT, rWih,
                                     rbih, rbhh, linW, linb, dout);
}

// Round 13
// 2373.792 us; speedup vs baseline: 2.1115x; 2.1113x over previous
//
#include <hip/hip_runtime.h>
#include <hip/hip_bf16.h>

typedef unsigned short u16;
typedef unsigned int u32;
typedef unsigned long long u64;

#define HD 512
#define BATCH 128
#define TENC 512
#define WPAD 520   // LDS row stride in bf16 elems (even -> u32-aligned rows)

typedef float f32x4 __attribute__((ext_vector_type(4)));
typedef short s16x8 __attribute__((ext_vector_type(8)));

__device__ __forceinline__ u16 f2b(float f) {
    u32 u = __float_as_uint(f);
    u32 r = (u + 0x7FFFu + ((u >> 16) & 1u)) >> 16;   // RNE
    return (u16)r;
}
__device__ __forceinline__ float b2f(u16 h) {
    return __uint_as_float(((u32)h) << 16);
}
__device__ __forceinline__ float sigm(float z) { return 1.0f / (1.0f + __expf(-z)); }
__device__ __forceinline__ float tanh_f(float z) { return 1.0f - 2.0f / (__expf(2.0f * z) + 1.0f); }

// ---------------------------------------------------------------------------
// init: seed tagged h-buffer. Layout: hb64[(g*2+parity)*4096 + b*256 + jp]
//   word = (bf16 h[2jp] | bf16 h[2jp+1]<<16) | ((u64)tag << 32)
// parity0 holds h_0 with tag 0; parity1 zeroed (tag 0, never matches t>=1).
// Also build rnn_Whh transposed bf16 [k][j] for coalesced decoder reads.
// ---------------------------------------------------------------------------
__global__ void init_misc(const float* __restrict__ h0, const float* __restrict__ rWhh,
                          u64* __restrict__ hb64, u16* __restrict__ rT) {
    int idx = blockIdx.x * 256 + threadIdx.x;      // 512 blocks x 256 = 131072
    if (idx < 65536) {                              // 8 g x 2 parity x 4096 words
        int g   = idx >> 13;
        int r   = idx & 8191;
        int p   = r >> 12;
        int ofs = r & 4095;
        int b   = ofs >> 8, jp = ofs & 255;
        u64 v = 0ull;                               // tag 0
        if (p == 0) {
            const float* hrow = h0 + (size_t)(g * 16 + b) * HD + jp * 2;
            u32 lo = (u32)f2b(hrow[0]) | ((u32)f2b(hrow[1]) << 16);
            v = (u64)lo;                            // tag 0 for h_0
        }
        hb64[(size_t)(g * 2 + p) * 4096 + b * 256 + jp] = v;
    }
    for (int i = idx; i < 262144; i += 131072) {    // rT[k*512+j] = rWhh[j][k]
        int k = i >> 9, j = i & 511;
        rT[i] = f2b(rWhh[j * 512 + k]);
    }
}

// ---------------------------------------------------------------------------
// Encoder LSTM: 8 batch-groups x 16 wgs (round-1 proven protocol).
// Cross-wg h handoff via SELF-VALIDATING tagged 64-bit words: {bf16 pair,
// step tag} in one atomic dwordx2 agent-scope store. Readers poll the data
// words until tag==t. Parity-2 buffering (writer of h_{t+1} has consumed all
// of h_t, hence all readers are done with h_{t-1}).
// ---------------------------------------------------------------------------
__global__ __launch_bounds__(512, 2) void enc_lstm(
    const float* __restrict__ xseq, const float* __restrict__ c0,
    const float* __restrict__ Wih, const float* __restrict__ Whh,
    const float* __restrict__ bih, const float* __restrict__ bhh,
    u16* __restrict__ enc, u64* __restrict__ hb64) {

    __shared__ u16 hlds[16 * WPAD];     // 16640 B: staged h tile [16b][512k] bf16
    __shared__ float exg[16 * 132];     // 8448 B: gate pre-activations [b][128 rows]
    __shared__ float bias_l[128];
    __shared__ float wih_l[128];

    const int tid = threadIdx.x;
    const int g = blockIdx.x & 7;       // batch group
    const int sl = blockIdx.x >> 3;     // hidden slot 0..15

    if (tid < 128) {
        int n = (tid >> 5) * 512 + sl * 32 + (tid & 31);
        bias_l[tid] = bih[n] + bhh[n];
        wih_l[tid] = Wih[n];
    }

    const int bT = tid >> 5, jl = tid & 31;               // cell-update mapping
    float c = c0[(g * 16 + bT) * HD + sl * 32 + jl];      // persistent cell state

    const int lane = tid & 63, wv = tid >> 6;
    const int q = lane >> 4, cl = lane & 15;
    const int R = (wv >> 1) * 32 + (wv & 1) * 16;         // wave's 16 gate-rows

    // hoist this lane's 16 B-fragments of Whh into registers (64 VGPRs)
    s16x8 bw[16];
    {
        int r = R + cl;
        int grow = (r >> 5) * 512 + sl * 32 + (r & 31);
        const float* wrow = Whh + (size_t)grow * 512;
        #pragma unroll
        for (int ks = 0; ks < 16; ++ks) {
            s16x8 v;
            #pragma unroll
            for (int j = 0; j < 8; ++j)
                v[j] = (short)f2b(wrow[ks * 32 + q * 8 + j]);
            bw[ks] = v;
        }
    }

    u32* hlds32 = (u32*)hlds;
    __syncthreads();

    const int jgl = sl * 32 + jl;
    u64* dpl0 = hb64 + (size_t)(g * 2) * 4096 + bT * 256 + (jgl >> 1);
    u64* dpl1 = dpl0 + 4096;

    for (int t = 0; t < TENC; ++t) {
        // ---- stage h_t: poll tagged words of buf[t&1] until tag==t
        const u64* src = hb64 + (size_t)(g * 2 + (t & 1)) * 4096;
        const u32 want = (u32)t;
        u64 vv[8];
        #pragma unroll
        for (int i = 0; i < 8; ++i)
            vv[i] = __hip_atomic_load(src + tid + i * 512, __ATOMIC_RELAXED,
                                      __HIP_MEMORY_SCOPE_AGENT);
        float xv = xseq[t * BATCH + g * 16 + bT];   // prefetched; used post-MFMA
        for (;;) {
            bool ok = true;
            #pragma unroll
            for (int i = 0; i < 8; ++i) {
                if ((u32)(vv[i] >> 32) != want) {
                    ok = false;
                    vv[i] = __hip_atomic_load(src + tid + i * 512, __ATOMIC_RELAXED,
                                              __HIP_MEMORY_SCOPE_AGENT);
                }
            }
            if (ok) break;
        }
        #pragma unroll
        for (int i = 0; i < 8; ++i) {
            int idx = tid + i * 512;
            hlds32[(idx >> 8) * 260 + (idx & 255)] = (u32)vv[i];
        }
        __syncthreads();                            // S1: hlds ready

        // dual accumulators: halve the dependent MFMA chain
        f32x4 acc0 = {0.f, 0.f, 0.f, 0.f}, acc1 = {0.f, 0.f, 0.f, 0.f};
        #pragma unroll
        for (int ks = 0; ks < 16; ks += 2) {
            s16x8 av0 = *(const s16x8*)&hlds[cl * WPAD + ks * 32 + q * 8];
            s16x8 av1 = *(const s16x8*)&hlds[cl * WPAD + (ks + 1) * 32 + q * 8];
            acc0 = __builtin_amdgcn_mfma_f32_16x16x32_bf16(av0, bw[ks], acc0, 0, 0, 0);
            acc1 = __builtin_amdgcn_mfma_f32_16x16x32_bf16(av1, bw[ks + 1], acc1, 0, 0, 0);
        }
        f32x4 acc = acc0 + acc1;
        #pragma unroll
        for (int r4 = 0; r4 < 4; ++r4)
            exg[(q * 4 + r4) * 132 + R + cl] = acc[r4];   // D: row m=q*4+r4, col n=cl
        __syncthreads();                            // S2: exg ready + hlds reads done

        // LSTM cell for (bT, jl)
        const float* exb = &exg[bT * 132];
        float gi = exb[jl]      + xv * wih_l[jl]      + bias_l[jl];
        float gf = exb[32 + jl] + xv * wih_l[32 + jl] + bias_l[32 + jl];
        float gg = exb[64 + jl] + xv * wih_l[64 + jl] + bias_l[64 + jl];
        float go = exb[96 + jl] + xv * wih_l[96 + jl] + bias_l[96 + jl];
        c = sigm(gf) * c + sigm(gi) * tanh_f(gg);
        float hv = sigm(go) * tanh_f(c);
        u16 h16 = f2b(hv);

        // tagged h_{t+1} store: pair + tag in ONE atomic 8B store (critical path)
        u32 me = (u32)h16;
        u32 up = (u32)__shfl_down((int)me, 1, 64);
        if ((jl & 1) == 0) {
            u64 word = (u64)(me | (up << 16)) | ((u64)(u32)(t + 1) << 32);
            __hip_atomic_store(((t + 1) & 1) ? dpl1 : dpl0, word,
                               __ATOMIC_RELAXED, __HIP_MEMORY_SCOPE_AGENT);
        }
        // enc write AFTER the handoff store: off the critical path
        enc[((size_t)t * BATCH + g * 16 + bT) * HD + jgl] = h16;
    }
}

// ---------------------------------------------------------------------------
// Fused decoder: one wg per batch row, 32 steps; grid 128 on 256 CUs, so
// each wg owns a CU -> VGPR is free (launch_bounds 512,1).
// p2: 8 t per iteration. 8 independent dots, then all 8 butterfly reduces
// batched (6 dependent stages with 8-way ILP instead of 48 dependent
// stages), ONE online-softmax rescale per 8-t block, e[8][8] kept in
// registers for the ctx update. (Round-6 proven; manual depth-2 variants
// all triggered a 128-VGPR cap + ~100MB scratch spill -- do not reorder.)
// ---------------------------------------------------------------------------
__global__ __launch_bounds__(512, 1) void dec_all(
    const float* __restrict__ xlast, const u16* __restrict__ enc,
    const u16* __restrict__ rT, const float* __restrict__ rWih,
    const float* __restrict__ rbih, const float* __restrict__ rbhh,
    const float* __restrict__ linW, const float* __restrict__ linb,
    float* __restrict__ dout) {

    __shared__ float hp[512];          // h entering the step
    __shared__ float ctxl[8 * 512];    // p1 partials, then p2 ctx partials
    __shared__ float red[512];         // hn broadcast, then reduce slots
    __shared__ float mw[8], lw[8];
    __shared__ float xsh;

    const int tid = threadIdx.x;
    const int b = blockIdx.x;
    const int wv = tid >> 6, lane = tid & 63;

    hp[tid] = b2f(enc[(size_t)511 * BATCH * HD + b * HD + tid]);  // h_enc
    float x = xlast[b];
    const float bia = rbih[tid] + rbhh[tid];
    const float wih = rWih[tid];
    const float lwt = linW[tid];
    const float lb = linb[0];
    const uint4* rT4 = (const uint4*)rT;                 // [512 k][64 chunks]
    const u16* ebase = enc + (size_t)b * HD + lane * 8;  // t-stride = 65536 elems
    __syncthreads();

    for (int s = 0; s < 32; ++s) {
        // ---- phase 1: wave wv covers k in [wv*64, wv*64+64)
        float pa[8] = {0, 0, 0, 0, 0, 0, 0, 0};
        const uint4* base = rT4 + (size_t)(wv * 64) * 64 + lane;
        #pragma unroll 4
        for (int kk = 0; kk < 64; ++kk) {
            float hk = hp[wv * 64 + kk];
            uint4 w = base[kk * 64];
            pa[0] = fmaf(hk, b2f((u16)(w.x & 0xFFFF)), pa[0]);
            pa[1] = fmaf(hk, b2f((u16)(w.x >> 16)),    pa[1]);
            pa[2] = fmaf(hk, b2f((u16)(w.y & 0xFFFF)), pa[2]);
            pa[3] = fmaf(hk, b2f((u16)(w.y >> 16)),    pa[3]);
            pa[4] = fmaf(hk, b2f((u16)(w.z & 0xFFFF)), pa[4]);
            pa[5] = fmaf(hk, b2f((u16)(w.z >> 16)),    pa[5]);
            pa[6] = fmaf(hk, b2f((u16)(w.w & 0xFFFF)), pa[6]);
            pa[7] = fmaf(hk, b2f((u16)(w.w >> 16)),    pa[7]);
        }
        #pragma unroll
        for (int i = 0; i < 8; ++i) ctxl[wv * 512 + lane * 8 + i] = pa[i];
        __syncthreads();

        float a = bia + x * wih;
        #pragma unroll
        for (int i = 0; i < 8; ++i) a += ctxl[i * 512 + tid];
        float hv = tanh_f(a);
        red[tid] = hv;                  // hn broadcast
        __syncthreads();

        // ---- phase 2: wave wv handles t = it*64 + i*8 + wv, 8 t per iter
        float h8[8];
        #pragma unroll
        for (int i = 0; i < 8; ++i) h8[i] = red[lane * 8 + i];
        float m = -1e30f, l = 0.f;
        float acc[8] = {0, 0, 0, 0, 0, 0, 0, 0};

        uint4 buf[8];
        #pragma unroll
        for (int i = 0; i < 8; ++i)
            buf[i] = *(const uint4*)(ebase + (size_t)(i * 8 + wv) * 65536);

        for (int it = 0; it < 8; ++it) {
            uint4 nxt[8];
            if (it < 7) {
                #pragma unroll
                for (int i = 0; i < 8; ++i)
                    nxt[i] = *(const uint4*)(ebase +
                               (size_t)((it + 1) * 64 + i * 8 + wv) * 65536);
            }
            float e[8][8], sp[8];
            #pragma unroll
            for (int i = 0; i < 8; ++i) {
                uint4 ev = buf[i];
                e[i][0] = b2f((u16)(ev.x & 0xFFFF)); e[i][1] = b2f((u16)(ev.x >> 16));
                e[i][2] = b2f((u16)(ev.y & 0xFFFF)); e[i][3] = b2f((u16)(ev.y >> 16));
                e[i][4] = b2f((u16)(ev.z & 0xFFFF)); e[i][5] = b2f((u16)(ev.z >> 16));
                e[i][6] = b2f((u16)(ev.w & 0xFFFF)); e[i][7] = b2f((u16)(ev.w >> 16));
                float sd = 0.f;
                #pragma unroll
                for (int j = 0; j < 8; ++j) sd = fmaf(e[i][j], h8[j], sd);
                sp[i] = sd;
            }
            // batched butterfly: 6 dependent stages, 8-way ILP
            #pragma unroll
            for (int mk = 1; mk < 64; mk <<= 1) {
                #pragma unroll
                for (int i = 0; i < 8; ++i) sp[i] += __shfl_xor(sp[i], mk, 64);
            }
            float pm = sp[0];
            #pragma unroll
            for (int i = 1; i < 8; ++i) pm = fmaxf(pm, sp[i]);
            if (pm > m) {                           // one rescale per 8-t block
                float sc = __expf(m - pm);
                l *= sc;
                #pragma unroll
                for (int j = 0; j < 8; ++j) acc[j] *= sc;
                m = pm;
            }
            #pragma unroll
            for (int i = 0; i < 8; ++i) {
                float p = __expf(sp[i] - m);
                l += p;
                #pragma unroll
                for (int j = 0; j < 8; ++j) acc[j] = fmaf(p, e[i][j], acc[j]);
            }
            if (it < 7) {
                #pragma unroll
                for (int i = 0; i < 8; ++i) buf[i] = nxt[i];
            }
        }
        if (lane == 0) { mw[wv] = m; lw[wv] = l; }
        #pragma unroll
        for (int i = 0; i < 8; ++i) ctxl[wv * HD + lane * 8 + i] = acc[i];
        __syncthreads();

        // ---- phase 3: merge online-softmax states, project, relu
        float M = mw[0];
        #pragma unroll
        for (int i = 1; i < 8; ++i) M = fmaxf(M, mw[i]);
        float L = 0.f, aw[8];
        #pragma unroll
        for (int i = 0; i < 8; ++i) { aw[i] = __expf(mw[i] - M); L += aw[i] * lw[i]; }
        float cj = 0.f;
        #pragma unroll
        for (int i = 0; i < 8; ++i) cj = fmaf(aw[i], ctxl[i * HD + tid], cj);
        float r = cj * lwt;
        #pragma unroll
        for (int mk = 1; mk < 64; mk <<= 1) r += __shfl_xor(r, mk, 64);
        if (lane == 0) red[wv] = r;
        __syncthreads();
        if (tid == 0) {
            float o = (red[0] + red[1] + red[2] + red[3] +
                       red[4] + red[5] + red[6] + red[7]) / L + lb;
            o = fmaxf(o, 0.f);
            dout[s * BATCH + b] = o;
            xsh = o;
        }
        __syncthreads();
        x = xsh;
        hp[tid] = hv;                   // h for next step
        __syncthreads();
    }
}

// ---------------------------------------------------------------------------
extern "C" void kernel_launch(void* const* d_in, const int* in_sizes, int n_in,
                              void* d_out, int out_size, void* d_ws, size_t ws_size,
                              hipStream_t stream) {
    const float* xseq = (const float*)d_in[0];   // [513,128,1]
    const float* h0   = (const float*)d_in[1];
    const float* c0   = (const float*)d_in[2];
    const float* Wih  = (const float*)d_in[3];   // [2048,1]
    const float* Whh  = (const float*)d_in[4];   // [2048,512]
    const float* bih  = (const float*)d_in[5];
    const float* bhh  = (const float*)d_in[6];
    const float* rWih = (const float*)d_in[7];   // [512,1]
    const float* rWhh = (const float*)d_in[8];   // [512,512]
    const float* rbih = (const float*)d_in[9];
    const float* rbhh = (const float*)d_in[10];
    const float* linW = (const float*)d_in[11];  // [1,512]
    const float* linb = (const float*)d_in[12];
    float* dout = (float*)d_out;                 // [32,128,1]

    // workspace layout
    char* ws = (char*)d_ws;
    u16* enc  = (u16*)ws;                                  // 64 MB
    u16* rT   = (u16*)(ws + 67108864);                     // 512 KB
    u64* hb64 = (u64*)(ws + 67108864 + 524288);            // 512 KB tagged h

    init_misc<<<512, 256, 0, stream>>>(h0, rWhh, hb64, rT);
    enc_lstm<<<128, 512, 0, stream>>>(xseq, c0, Wih, Whh, bih, bhh, enc, hb64);
    dec_all<<<128, 512, 0, stream>>>(xseq + 512 * BATCH, enc, rT, rWih,
                                     rbih, rbhh, linW, linb, dout);
}